// Round 2
// baseline (584.338 us; speedup 1.0000x reference)
//
#include <hip/hip_runtime.h>
#include <hip/hip_bf16.h>
#include <stdint.h>

// BcosGCNLayer: out[n,o] = lin * |lin| / (R_n * C_o),  lin = z @ W^T
// R2: XOR-swizzled LDS (kill 16-way ds_read conflicts), LDS-bounce epilogue
// (full-line f32x4 stores, kill ~260MB RMW traffic), z register prefetch.

constexpr int KDIM = 512;
constexpr int NDIM = 512;

typedef __attribute__((ext_vector_type(8))) short bf16x8;   // MFMA A/B frag (4 VGPR)
typedef __attribute__((ext_vector_type(4))) float f32x4;    // MFMA C/D frag
typedef __attribute__((ext_vector_type(4))) uint32_t u32x4; // 16B LDS store

__device__ __forceinline__ uint32_t pk_bf16(float a, float b) {
  __hip_bfloat162 h = __float22bfloat162_rn(make_float2(a, b));
  union { __hip_bfloat162 h2; uint32_t u; } c;
  c.h2 = h;
  return c.u;
}

__device__ __forceinline__ void gload_lds16(const void* g, void* lds) {
  __builtin_amdgcn_global_load_lds(
      (const __attribute__((address_space(1))) uint32_t*)(uintptr_t)g,
      (__attribute__((address_space(3))) uint32_t*)(uintptr_t)lds,
      16, 0, 0);
}

// ---------- prep: W fp32 -> bf16, and 1/max(||w_o||,eps) ----------
__global__ __launch_bounds__(128) void prep_w(const float* __restrict__ w,
                                              unsigned short* __restrict__ wb,
                                              float* __restrict__ cninv) {
  const int row = blockIdx.x;
  const int t   = threadIdx.x;
  const float* gp = w + (size_t)row * KDIM + t * 4;
  f32x4 v = *(const f32x4*)gp;
  float s = v.x * v.x + v.y * v.y + v.z * v.z + v.w * v.w;

  uint2 p;
  p.x = pk_bf16(v.x, v.y);
  p.y = pk_bf16(v.z, v.w);
  *(uint2*)(wb + (size_t)row * KDIM + t * 4) = p;

  #pragma unroll
  for (int off = 32; off > 0; off >>= 1) s += __shfl_down(s, off, 64);
  __shared__ float red[2];
  if ((t & 63) == 0) red[t >> 6] = s;
  __syncthreads();
  if (t == 0) cninv[row] = 1.0f / fmaxf(sqrtf(red[0] + red[1]), 1e-12f);
}

// ---------- main fused GEMM ----------
// 128x128 block tile, BK=64, 4 waves x (64x64). LDS tiles stored as 16B
// granules: granule (r, c) lives at chunk (c ^ (r&7)) of row r.
struct SMemMM { unsigned short As[128 * 64]; unsigned short Bs[128 * 64]; };  // 32 KB
union SMemU {
  SMemMM mm;
  float ep[4 * 32 * 68];  // epilogue staging: 4 waves x [32][68] fp32, 34816 B
};

__global__ __launch_bounds__(256) void gemm_bcos(const float* __restrict__ z,
                                                 const unsigned short* __restrict__ wb,
                                                 const float* __restrict__ cninv,
                                                 float* __restrict__ out, int M) {
  __shared__ SMemU sm;
  __shared__ float rowsq[128];
  __shared__ float rinv[128];

  const int t    = threadIdx.x;
  const int nb   = blockIdx.x;  // 0..3
  const int mb   = blockIdx.y;
  const int w    = t >> 6;
  const int lane = t & 63;
  const int lrow = lane & 15;
  const int quad = lane >> 4;
  const int wm   = (w & 1) * 64;
  const int wn   = (w >> 1) * 64;

  if (t < 128) rowsq[t] = 0.0f;

  f32x4 acc[4][4];
  #pragma unroll
  for (int i = 0; i < 4; ++i)
    #pragma unroll
    for (int j = 0; j < 4; ++j) acc[i][j] = (f32x4)0.0f;

  // Staging geometry (loop-invariant): granule gidx = t + 256*i -> (r, c)
  int rr[4];           // A row per i
  size_t gbase[4];     // z global float offset (row base + c*8)
  int aoff[4];         // As swizzled element offset for ds_write
  size_t boff[4];      // wb global element offset (row base + swizzled source chunk)
  int bdst[4];         // Bs element offset for DMA dst (lane-contiguous, unswizzled)
  #pragma unroll
  for (int i = 0; i < 4; ++i) {
    const int gidx = t + 256 * i;
    const int r = gidx >> 3, c = gidx & 7;
    rr[i] = r;
    int grow = mb * 128 + r;
    if (grow >= M) grow = M - 1;           // tail clamp (stores guarded)
    gbase[i] = (size_t)grow * KDIM + c * 8;
    aoff[i]  = (r * 8 + (c ^ (r & 7))) * 8;
    boff[i]  = (size_t)(nb * 128 + r) * KDIM + (size_t)((c ^ (r & 7)) * 8);
    bdst[i]  = gidx * 8;
  }

  float sq[4] = {0.f, 0.f, 0.f, 0.f};

  // initial z prefetch (kk = 0)
  f32x4 zr0[4], zr1[4];
  #pragma unroll
  for (int i = 0; i < 4; ++i) {
    const float* gp = z + gbase[i];
    zr0[i] = *(const f32x4*)gp;
    zr1[i] = *(const f32x4*)(gp + 4);
  }

  for (int kk = 0; kk < 8; ++kk) {
    const int kbase = kk * 64;
    __syncthreads();  // prev MFMA done reading LDS

    // B tile: async DMA (global source carries the swizzle permutation)
    #pragma unroll
    for (int i = 0; i < 4; ++i)
      gload_lds16(wb + boff[i] + kbase, &sm.mm.Bs[bdst[i]]);

    // A tile: current z regs -> sumsq -> bf16 -> swizzled ds_write_b128
    #pragma unroll
    for (int i = 0; i < 4; ++i) {
      const f32x4 v0 = zr0[i], v1 = zr1[i];
      sq[i] += v0.x * v0.x + v0.y * v0.y + v0.z * v0.z + v0.w * v0.w +
               v1.x * v1.x + v1.y * v1.y + v1.z * v1.z + v1.w * v1.w;
      u32x4 p;
      p.x = pk_bf16(v0.x, v0.y);
      p.y = pk_bf16(v0.z, v0.w);
      p.z = pk_bf16(v1.x, v1.y);
      p.w = pk_bf16(v1.z, v1.w);
      *(u32x4*)&sm.mm.As[aoff[i]] = p;
    }

    // prefetch z for kk+1 — drains alongside the B DMA at the barrier
    if (kk < 7) {
      #pragma unroll
      for (int i = 0; i < 4; ++i) {
        const float* gp = z + gbase[i] + kbase + 64;
        zr0[i] = *(const f32x4*)gp;
        zr1[i] = *(const f32x4*)(gp + 4);
      }
    }

    __syncthreads();  // drains DMA + prefetch together

    #pragma unroll
    for (int ks = 0; ks < 2; ++ks) {
      const int cc = ks * 4 + quad;  // k-chunk index 0..7
      bf16x8 a[4], b[4];
      #pragma unroll
      for (int x = 0; x < 4; ++x) {
        const int ra = wm + x * 16 + lrow;
        const int rb = wn + x * 16 + lrow;
        a[x] = *(const bf16x8*)&sm.mm.As[(ra * 8 + (cc ^ (ra & 7))) * 8];
        b[x] = *(const bf16x8*)&sm.mm.Bs[(rb * 8 + (cc ^ (rb & 7))) * 8];
      }
      #pragma unroll
      for (int mt = 0; mt < 4; ++mt)
        #pragma unroll
        for (int nt = 0; nt < 4; ++nt)
          acc[mt][nt] = __builtin_amdgcn_mfma_f32_16x16x32_bf16(a[mt], b[nt], acc[mt][nt], 0, 0, 0);
    }
  }

  // z row norms
  #pragma unroll
  for (int i = 0; i < 4; ++i) atomicAdd(&rowsq[rr[i]], sq[i]);
  __syncthreads();
  if (t < 128) rinv[t] = 1.0f / fmaxf(sqrtf(rowsq[t]), 1e-12f);
  __syncthreads();  // also: all waves done with As/Bs -> ep aliasing safe

  // epilogue: scale in-register, bounce via wave-private padded LDS,
  // store row-contiguous f32x4 (full 128B lines).
  float cv[4];
  #pragma unroll
  for (int nt = 0; nt < 4; ++nt) cv[nt] = cninv[nb * 128 + wn + nt * 16 + lrow];

  float* ep = &sm.ep[w * 32 * 68];
  #pragma unroll
  for (int ch = 0; ch < 2; ++ch) {
    #pragma unroll
    for (int half = 0; half < 2; ++half) {
      const int mt = ch * 2 + half;
      #pragma unroll
      for (int nt = 0; nt < 4; ++nt) {
        #pragma unroll
        for (int i = 0; i < 4; ++i) {
          const int lr = wm + mt * 16 + quad * 4 + i;       // row within block
          const float v = acc[mt][nt][i];
          ep[(half * 16 + quad * 4 + i) * 68 + nt * 16 + lrow] =
              v * fabsf(v) * rinv[lr] * cv[nt];
        }
      }
    }
    // wave-private: in-order LDS per wave, compiler inserts lgkmcnt wait
    #pragma unroll
    for (int p = 0; p < 8; ++p) {
      const int rl = p * 4 + (lane >> 4);
      const int c4 = (lane & 15) * 4;
      const f32x4 v = *(const f32x4*)&ep[rl * 68 + c4];
      const int grow = mb * 128 + wm + ch * 32 + rl;
      if (grow < M)
        *(f32x4*)&out[(size_t)grow * NDIM + nb * 128 + wn + c4] = v;
    }
  }
}

extern "C" void kernel_launch(void* const* d_in, const int* in_sizes, int n_in,
                              void* d_out, int out_size, void* d_ws, size_t ws_size,
                              hipStream_t stream) {
  const float* z = (const float*)d_in[0];
  const float* w = (const float*)d_in[1];
  float* out = (float*)d_out;
  const int M = in_sizes[0] / KDIM;

  unsigned short* wb = (unsigned short*)d_ws;
  float* cninv = (float*)((char*)d_ws + (size_t)NDIM * KDIM * 2);

  prep_w<<<dim3(NDIM), dim3(128), 0, stream>>>(w, wb, cninv);

  dim3 grid(NDIM / 128, (M + 127) / 128);
  gemm_bcos<<<grid, dim3(256), 0, stream>>>(z, wb, cninv, out, M);
}